// Round 8
// baseline (274.367 us; speedup 1.0000x reference)
//
#include <hip/hip_runtime.h>
#include <hip/hip_bf16.h>

// Problem constants (B=4, C=64, N=8192, K=16, D=64)
#define NPTS 8192
#define NQ   32768      // B*N
#define KNN  16
#define SCAP 112        // survivor cap per query (expected ~25-50)

// ws layout (bytes)
#define OFF_XT   0                      // B*N*C f32 = 8 MB  (x transposed to (B,N,C))
#define OFF_FBIG (8*1024*1024)          // 17*64*64 f32 = 278528 B (F with appended -sum(F))
#define OFF_SUMS (OFF_FBIG + 278528)    // 128 f32 (sum, sumsq per channel)
#define OFF_IDX  (OFF_SUMS + 512)       // B*N*16 int32 = 2 MB
#define OFF_PRE  (OFF_IDX + 2*1024*1024)// B*N*64 f32 = 8 MB (pre-BN output, (B*N, D))
// sq array (B*N f32 = 128 KB) ALIASES the start of PRE: k_prep writes it,
// k_knn consumes it, then k_conv overwrites PRE — stream-ordered, safe.
#define OFF_SQ   OFF_PRE

typedef float f2 __attribute__((ext_vector_type(2)));

// Reference fp32 key — numpy execution model (verified R6, absmax 0.0156):
//   sq[m]   = (x*x + y*y) + z*z                  -- non-fused (np.sum(pos*pos))
//   inner   = fma(z,z', fma(y,y', rnd(x*x')))    -- einsum AVX2 axpy FMA chain
//   negd    = ((2*inner) - sq_n) - sq_m          -- elementwise, left-to-right
__device__ __forceinline__ float sq3(float x, float y, float z) {
    #pragma clang fp contract(off)
    float xx = x * x;
    float yy = y * y;
    float zz = z * z;
    return (xx + yy) + zz;
}
__device__ __forceinline__ float negd2(float qx, float qy, float qz, float sqn,
                                       float mx, float my, float mz, float sqm) {
    #pragma clang fp contract(off)
    float p0 = qx * mx;
    float inn = __builtin_fmaf(qz, mz, __builtin_fmaf(qy, my, p0));
    float t = 2.0f * inn;
    float u = t - sqn;
    return u - sqm;
}
// Filter margin: cheap fused key c~ = 2<q,m> - sqm differs from (exact key +
// sqn) by <= ~1e-4. 2e-3 is 20x conservative; two eps-steps cover tau-side
// and member-side error -> survivor set provably supersets the true top-16.
#define KEY_EPS2 2.0e-3f

// uniform-load helper: value is wave-uniform -> pin to SGPR
__device__ __forceinline__ float rfl(float v) {
    return __uint_as_float(__builtin_amdgcn_readfirstlane(__float_as_uint(v)));
}

// ---------------- K0: merged prep (transpose x | Fbig | zero sums | sq) ------
// blocks 0..511: transpose x. 512..527: Fbig j. 528: Fbig[16]=-sum. 529: zero
// sums. 530..657: sq per point (exact reference rounding).
__global__ __launch_bounds__(256) void k_prep(const float* __restrict__ x,
                                              const float* __restrict__ F,
                                              const float* __restrict__ pos,
                                              float* __restrict__ xT,
                                              float* __restrict__ Fb,
                                              float* __restrict__ sums,
                                              float* __restrict__ sqa) {
    int bid = blockIdx.x;
    if (bid < 512) {
        __shared__ float tile[64][65];
        int lane = threadIdx.x & 63, wid = threadIdx.x >> 6;
        int b = bid >> 7, nt = bid & 127;
        int n0 = nt * 64;
        for (int rr = 0; rr < 16; ++rr) {
            int c = wid * 16 + rr;
            tile[c][lane] = x[((size_t)b * 64 + c) * NPTS + n0 + lane];
        }
        __syncthreads();
        for (int rr = 0; rr < 16; ++rr) {
            int r = wid * 16 + rr;
            xT[((size_t)(b * NPTS + n0 + r)) * 64 + lane] = tile[lane][r];
        }
    } else if (bid < 528) {
        int j = bid - 512;
        for (int e = threadIdx.x; e < 4096; e += 256)
            Fb[j * 4096 + e] = F[j * 4096 + e];
    } else if (bid == 528) {
        for (int e = threadIdx.x; e < 4096; e += 256) {
            float s = 0.f;
            for (int k = 0; k < 16; ++k) s += F[k * 4096 + e];
            Fb[16 * 4096 + e] = -s;
        }
    } else if (bid == 529) {
        if (threadIdx.x < 128) sums[threadIdx.x] = 0.f;
    } else {
        int g = (bid - 530) * 256 + threadIdx.x;   // 0..NQ-1
        int b = g >> 13, n = g & (NPTS - 1);
        const float* pb = pos + (size_t)b * 3 * NPTS;
        sqa[g] = sq3(pb[n], pb[NPTS + n], pb[2 * NPTS + n]);
    }
}

// Radix-ballot select: thr[i] = (16th largest of 64 lane values lm[i]) - eps.
// Exact 16th-of-lane-maxima over the FULL candidate set (R3 lesson: prefix
// thresholds explode survivor counts 5-8x — never again).
__device__ __forceinline__ void sel16(const float* lm, float* thr) {
    unsigned up[4], pfx[4];
    #pragma unroll
    for (int i = 0; i < 4; ++i) {
        unsigned s = __float_as_uint(lm[i]);
        up[i]  = s ^ ((unsigned)((int)s >> 31) | 0x80000000u);
        pfx[i] = 0u;
    }
    for (int bit = 31; bit >= 0; --bit) {
        unsigned bmask = 1u << bit;
        #pragma unroll
        for (int i = 0; i < 4; ++i) {
            unsigned trial = pfx[i] | bmask;
            unsigned long long m = __ballot(up[i] >= trial);
            if (__popcll(m) >= 16) pfx[i] = trial;
        }
    }
    #pragma unroll
    for (int i = 0; i < 4; ++i) {
        unsigned p = pfx[i];
        unsigned sbits = (p & 0x80000000u) ? (p ^ 0x80000000u) : ~p;
        thr[i] = __uint_as_float(sbits) - KEY_EPS2;
    }
}

// ---------------- K1: kNN, coop split + packed-fp32 scan (R25) ---------------
// R24 base (wave w scans chunk [w*2048,(w+1)*2048) for all 16 block queries;
// spill-free; 107 us, VALUBusy 73% == the scalar-scan issue floor of ~78 us).
// R25: cut issue slots with v_pk_fma_f32 (dual-rate packed fp32; R4 proved
// emission + real VALU-cycle cut, but that kernel was L2-bound so it didn't
// pay — this one is issue-bound, so it should). Register fit (R5/R6 lesson):
// pk needs VGPR-pair coeff splats; 16 q x 3 x 2 = 96 VGPRs won't fit, so the
// 16 queries are processed as TWO groups of 8 (48 VGPRs of splats), sweeping
// the wave's chunk twice per pass. Loads double (still ~1 GB L2 total, ~30 us
// at ceiling, overlapped); scan VALU drops 0.60x (78 -> ~47 us). All register
// arrays compile-time-indexed (g and i fully unrolled — rule-#20 audit).
__global__ __launch_bounds__(256, 4) void k_knn(const float* __restrict__ pos,
                                                const float* __restrict__ sqa,
                                                int* __restrict__ idxo) {
    __shared__ int   cnt[16];
    __shared__ int   outI[16][16];
    __shared__ float thrs[16];
    __shared__ union {
        float lm[16][256];                                  // pass-1 partials
        struct {                                            // pass-2 onward
            unsigned short sidx[16][SCAP];
            float          skey[16][SCAP];
        } ab;
    } sh;
    int t = threadIdx.x, lane = t & 63, wid = t >> 6;
    int qblk = blockIdx.x * 16;               // 16 queries per block, same batch
    int b = qblk >> 13;
    const float* px = pos + (size_t)b * 3 * NPTS;
    const float* py = px + NPTS;
    const float* pz = py + NPTS;
    const float* sb = sqa + (size_t)b * NPTS;
    int qn = qblk & (NPTS - 1);               // block's first query (in-batch)

    if (lane < 4) cnt[wid * 4 + lane] = 0;
    if (lane < 16) {
        #pragma unroll
        for (int i = 0; i < 4; ++i) outI[wid * 4 + i][lane] = qn + wid * 4 + i;
    }

    int base = wid * 2048;

    // pass 1: two query-groups of 8; pk-fma; publish lane-maxima per group
    #pragma unroll
    for (int g = 0; g < 2; ++g) {
        f2 sx[8], sy[8], sz[8];
        #pragma unroll
        for (int i = 0; i < 8; ++i) {
            float tx = 2.0f * px[qn + g * 8 + i];
            float ty = 2.0f * py[qn + g * 8 + i];
            float tz = 2.0f * pz[qn + g * 8 + i];
            sx[i] = (f2){tx, tx}; sy[i] = (f2){ty, ty}; sz[i] = (f2){tz, tz};
        }
        float lm[8];
        #pragma unroll
        for (int i = 0; i < 8; ++i) lm[i] = -3.4e38f;
        for (int it = 0; it < 8; ++it) {
            int m = base + it * 256 + lane * 4;
            float4 X = *(const float4*)(px + m);
            float4 Y = *(const float4*)(py + m);
            float4 Z = *(const float4*)(pz + m);
            float4 S = *(const float4*)(sb + m);
            f2 Xl = *(const f2*)&X, Xh = *((const f2*)&X + 1);
            f2 Yl = *(const f2*)&Y, Yh = *((const f2*)&Y + 1);
            f2 Zl = *(const f2*)&Z, Zh = *((const f2*)&Z + 1);
            f2 Sl = *(const f2*)&S, Sh = *((const f2*)&S + 1);
            #pragma unroll
            for (int i = 0; i < 8; ++i) {
                f2 alo = __builtin_elementwise_fma(sx[i], Xl,
                         __builtin_elementwise_fma(sy[i], Yl,
                         __builtin_elementwise_fma(sz[i], Zl, -Sl)));
                f2 ahi = __builtin_elementwise_fma(sx[i], Xh,
                         __builtin_elementwise_fma(sy[i], Yh,
                         __builtin_elementwise_fma(sz[i], Zh, -Sh)));
                float m012 = fmaxf(fmaxf(alo.x, alo.y), ahi.x);
                lm[i] = fmaxf(fmaxf(m012, ahi.y), lm[i]);
            }
        }
        #pragma unroll
        for (int i = 0; i < 8; ++i) sh.lm[g * 8 + i][wid * 64 + lane] = lm[i];
    }
    __syncthreads();

    // wave w: combine 4 waves' partials for queries 4w..4w+3, sel16 -> thrs
    {
        float comb[4];
        #pragma unroll
        for (int j = 0; j < 4; ++j) {
            int i = wid * 4 + j;
            float c0 = sh.lm[i][lane];
            float c1 = sh.lm[i][64 + lane];
            float c2 = sh.lm[i][128 + lane];
            float c3 = sh.lm[i][192 + lane];
            comb[j] = fmaxf(fmaxf(c0, c1), fmaxf(c2, c3));
        }
        float thr4[4];
        sel16(comb, thr4);
        // thr4 is lane-invariant (built from wave-uniform ballots); publish
        // via lane 0 with a fully-unrolled loop (NO runtime index into thr4).
        if (lane == 0) {
            #pragma unroll
            for (int j = 0; j < 4; ++j) thrs[wid * 4 + j] = thr4[j];
        }
    }
    __syncthreads();
    // block-uniform thresholds -> SGPRs (VOPC reads SGPR src)
    float thr[16];
    #pragma unroll
    for (int i = 0; i < 16; ++i) thr[i] = rfl(thrs[i]);

    // pass 2: two group-sweeps; pk keys, scalar cmp vs SGPR thresholds
    #pragma unroll
    for (int g = 0; g < 2; ++g) {
        f2 sx[8], sy[8], sz[8];
        #pragma unroll
        for (int i = 0; i < 8; ++i) {
            float tx = 2.0f * px[qn + g * 8 + i];
            float ty = 2.0f * py[qn + g * 8 + i];
            float tz = 2.0f * pz[qn + g * 8 + i];
            sx[i] = (f2){tx, tx}; sy[i] = (f2){ty, ty}; sz[i] = (f2){tz, tz};
        }
        for (int it = 0; it < 8; ++it) {
            int m = base + it * 256 + lane * 4;
            float4 X = *(const float4*)(px + m);
            float4 Y = *(const float4*)(py + m);
            float4 Z = *(const float4*)(pz + m);
            float4 S = *(const float4*)(sb + m);
            f2 Xl = *(const f2*)&X, Xh = *((const f2*)&X + 1);
            f2 Yl = *(const f2*)&Y, Yh = *((const f2*)&Y + 1);
            f2 Zl = *(const f2*)&Z, Zh = *((const f2*)&Z + 1);
            f2 Sl = *(const f2*)&S, Sh = *((const f2*)&S + 1);
            #pragma unroll
            for (int i = 0; i < 8; ++i) {
                int lq = g * 8 + i;   // compile-time (g,i both unrolled)
                f2 alo = __builtin_elementwise_fma(sx[i], Xl,
                         __builtin_elementwise_fma(sy[i], Yl,
                         __builtin_elementwise_fma(sz[i], Zl, -Sl)));
                f2 ahi = __builtin_elementwise_fma(sx[i], Xh,
                         __builtin_elementwise_fma(sy[i], Yh,
                         __builtin_elementwise_fma(sz[i], Zh, -Sh)));
                if (alo.x >= thr[lq]) { int s_ = atomicAdd(&cnt[lq],1); if (s_<SCAP) sh.ab.sidx[lq][s_] = (unsigned short)m; }
                if (alo.y >= thr[lq]) { int s_ = atomicAdd(&cnt[lq],1); if (s_<SCAP) sh.ab.sidx[lq][s_] = (unsigned short)(m+1); }
                if (ahi.x >= thr[lq]) { int s_ = atomicAdd(&cnt[lq],1); if (s_<SCAP) sh.ab.sidx[lq][s_] = (unsigned short)(m+2); }
                if (ahi.y >= thr[lq]) { int s_ = atomicAdd(&cnt[lq],1); if (s_<SCAP) sh.ab.sidx[lq][s_] = (unsigned short)(m+3); }
            }
        }
    }
    __syncthreads();

    // phase A: exact reference key per survivor (wave w: queries 4w..4w+3).
    // Query coords re-loaded from global (L1-hot) — runtime lq only indexes
    // MEMORY, never register arrays (R5 scratch lesson).
    #pragma unroll 1
    for (int i = 0; i < 4; ++i) {
        int lq = wid * 4 + i;
        float qxx = px[qn + lq], qyy = py[qn + lq], qzz = pz[qn + lq];
        float sqn = sb[qn + lq];
        int S = cnt[lq]; if (S > SCAP) S = SCAP;
        for (int p = lane; p < S; p += 64) {
            int m = sh.ab.sidx[lq][p];
            sh.ab.skey[lq][p] = negd2(qxx, qyy, qzz, sqn,
                                      px[m], py[m], pz[m], sb[m]);
        }
    }
    __syncthreads();

    // phase B: exact rerank; ties -> lower index (lax.top_k semantics)
    #pragma unroll 1
    for (int i = 0; i < 4; ++i) {
        int lq = wid * 4 + i;
        int S = cnt[lq]; if (S > SCAP) S = SCAP;
        for (int p = lane; p < S; p += 64) {
            int m = sh.ab.sidx[lq][p];
            float km = sh.ab.skey[lq][p];
            int rank = 0;
            for (int j = 0; j < S; ++j) {
                float kj = sh.ab.skey[lq][j];
                int ij = sh.ab.sidx[lq][j];
                if (kj > km || (kj == km && ij < m)) rank++;
            }
            if (rank < KNN) outI[lq][rank] = m;
        }
    }
    __syncthreads();
    // write out 16 queries x 16 ranks
    {
        int lq = t >> 4;
        idxo[(size_t)(qblk + lq) * KNN + (t & 15)] = outI[lq][t & 15];
    }
}

// ---------------- K2: gather + GEMM + fused BN-stats epilogue ----------------
// outp[q][d] = sum_{j=0..16} sum_c xT[nbr_j(q)][c] * Fbig[j][c][d]
// Tile: 64 q x 64 d, 256 threads, 4x4 micro (R9/R13 proven). Epilogue computes
// block-partial per-channel sum/sumsq from live accumulators (reusing Bt).
// R10/R14 both showed 128-thread variants regress (occupancy cliff).
#define CPAD 68
__global__ __launch_bounds__(256) void k_conv(const float* __restrict__ xT,
                                              const float* __restrict__ Fb,
                                              const int* __restrict__ idx,
                                              float* __restrict__ outp,
                                              float* __restrict__ sums) {
    __shared__ float At[64][CPAD];
    __shared__ float Bt[64 * 64];
    int t = threadIdx.x;
    int q0 = blockIdx.x * 64;                 // tile base (same batch: 8192%64==0)
    int bbase = q0 & ~(NPTS - 1);             // batch row offset in xT
    int qi0 = (t >> 4) * 4;                   // query sub-block 0..60
    int dj0 = (t & 15) * 4;                   // d sub-block 0..60
    int r = t & 63;                           // gather row
    int s = t >> 6;                           // 16-float segment

    float acc[4][4];
    #pragma unroll
    for (int a = 0; a < 4; ++a)
        #pragma unroll
        for (int bb = 0; bb < 4; ++bb) acc[a][bb] = 0.f;

    for (int j = 0; j < 17; ++j) {
        // ---- stage A: gather 64 neighbor rows, store transposed ----
        {
            int qg = q0 + r;
            int nbr = (j < 16) ? (idx[(size_t)qg * KNN + j] & (NPTS - 1))
                               : (qg & (NPTS - 1));
            const float* src = xT + ((size_t)(bbase + nbr) * 64 + s * 16);
            float4 v0 = *(const float4*)(src);
            float4 v1 = *(const float4*)(src + 4);
            float4 v2 = *(const float4*)(src + 8);
            float4 v3 = *(const float4*)(src + 12);
            int c0 = s * 16;
            At[c0+ 0][r] = v0.x; At[c0+ 1][r] = v0.y; At[c0+ 2][r] = v0.z; At[c0+ 3][r] = v0.w;
            At[c0+ 4][r] = v1.x; At[c0+ 5][r] = v1.y; At[c0+ 6][r] = v1.z; At[c0+ 7][r] = v1.w;
            At[c0+ 8][r] = v2.x; At[c0+ 9][r] = v2.y; At[c0+10][r] = v2.z; At[c0+11][r] = v2.w;
            At[c0+12][r] = v3.x; At[c0+13][r] = v3.y; At[c0+14][r] = v3.z; At[c0+15][r] = v3.w;
        }
        // ---- stage B: copy F[j] (4096 floats) ----
        {
            const float* fj = Fb + j * 4096;
            #pragma unroll
            for (int u = 0; u < 4; ++u) {
                int e = u * 1024 + t * 4;
                *(float4*)&Bt[e] = *(const float4*)(fj + e);
            }
        }
        __syncthreads();
        // ---- compute: 64 k-steps ----
        #pragma unroll 8
        for (int k = 0; k < 64; ++k) {
            float4 av = *(const float4*)&At[k][qi0];
            float4 bv = *(const float4*)&Bt[k * 64 + dj0];
            acc[0][0] = fmaf(av.x, bv.x, acc[0][0]);
            acc[0][1] = fmaf(av.x, bv.y, acc[0][1]);
            acc[0][2] = fmaf(av.x, bv.z, acc[0][2]);
            acc[0][3] = fmaf(av.x, bv.w, acc[0][3]);
            acc[1][0] = fmaf(av.y, bv.x, acc[1][0]);
            acc[1][1] = fmaf(av.y, bv.y, acc[1][1]);
            acc[1][2] = fmaf(av.y, bv.z, acc[1][2]);
            acc[1][3] = fmaf(av.y, bv.w, acc[1][3]);
            acc[2][0] = fmaf(av.z, bv.x, acc[2][0]);
            acc[2][1] = fmaf(av.z, bv.y, acc[2][1]);
            acc[2][2] = fmaf(av.z, bv.z, acc[2][2]);
            acc[2][3] = fmaf(av.z, bv.w, acc[2][3]);
            acc[3][0] = fmaf(av.w, bv.x, acc[3][0]);
            acc[3][1] = fmaf(av.w, bv.y, acc[3][1]);
            acc[3][2] = fmaf(av.w, bv.z, acc[3][2]);
            acc[3][3] = fmaf(av.w, bv.w, acc[3][3]);
        }
        __syncthreads();
    }
    // ---- epilogue 1: store outputs ----
    #pragma unroll
    for (int qi = 0; qi < 4; ++qi) {
        float4 o = make_float4(acc[qi][0], acc[qi][1], acc[qi][2], acc[qi][3]);
        *(float4*)(outp + (size_t)(q0 + qi0 + qi) * 64 + dj0) = o;
    }
    // ---- epilogue 2: fused BN stats (reuse Bt: P=sum, P2=sumsq; 16 q-groups) ----
    {
        float* P  = Bt;          // [16][64]
        float* P2 = Bt + 1024;   // [16][64]
        int g = t >> 4;          // q-group 0..15
        #pragma unroll
        for (int dd = 0; dd < 4; ++dd) {
            float sv = ((acc[0][dd] + acc[1][dd]) + acc[2][dd]) + acc[3][dd];
            float qv = fmaf(acc[3][dd], acc[3][dd],
                       fmaf(acc[2][dd], acc[2][dd],
                       fmaf(acc[1][dd], acc[1][dd], acc[0][dd] * acc[0][dd])));
            P [g * 64 + dj0 + dd] = sv;
            P2[g * 64 + dj0 + dd] = qv;
        }
        __syncthreads();
        if (t < 64) {
            float a = 0.f, b2 = 0.f;
            #pragma unroll
            for (int gg = 0; gg < 16; ++gg) {
                a  += P [gg * 64 + t];
                b2 += P2[gg * 64 + t];
            }
            atomicAdd(&sums[t], a);
            atomicAdd(&sums[64 + t], b2);
        }
    }
}

// ---------------- K3: BN + transpose (B,N,D) -> (B,D,N) ----------------
__global__ __launch_bounds__(256) void k_bn(const float* __restrict__ outp,
                                            const float* __restrict__ sums,
                                            const float* __restrict__ gamma,
                                            const float* __restrict__ beta,
                                            float* __restrict__ out) {
    __shared__ float tile[64][65];
    __shared__ float sa[64], sb[64];
    int lane = threadIdx.x & 63, wid = threadIdx.x >> 6;
    int b = blockIdx.x >> 7, nt = blockIdx.x & 127;
    int n0 = nt * 64;
    if (threadIdx.x < 64) {
        const float inv = 1.f / 32768.f;
        float mean = sums[threadIdx.x] * inv;
        float var = sums[64 + threadIdx.x] * inv - mean * mean;
        float rs = rsqrtf(var + 1e-5f);
        float a = rs * gamma[threadIdx.x];
        sa[threadIdx.x] = a;
        sb[threadIdx.x] = beta[threadIdx.x] - mean * a;
    }
    for (int rr = 0; rr < 16; ++rr) {
        int r = wid * 16 + rr;
        tile[r][lane] = outp[((size_t)(b * NPTS + n0 + r)) * 64 + lane];
    }
    __syncthreads();
    for (int rr = 0; rr < 16; ++rr) {
        int dr = wid * 16 + rr;
        out[((size_t)b * 64 + dr) * NPTS + n0 + lane] =
            fmaf(tile[lane][dr], sa[dr], sb[dr]);
    }
}

extern "C" void kernel_launch(void* const* d_in, const int* in_sizes, int n_in,
                              void* d_out, int out_size, void* d_ws, size_t ws_size,
                              hipStream_t stream) {
    (void)in_sizes; (void)n_in; (void)out_size; (void)ws_size;
    const float* x     = (const float*)d_in[0];  // (4,64,8192)
    const float* pos   = (const float*)d_in[1];  // (4,3,8192)
    const float* F     = (const float*)d_in[2];  // (16,64,64)
    const float* gamma = (const float*)d_in[3];  // (64,)
    const float* beta  = (const float*)d_in[4];  // (64,)
    float* out = (float*)d_out;                  // (4,64,8192)

    char* ws = (char*)d_ws;
    float* xT   = (float*)(ws + OFF_XT);
    float* Fb   = (float*)(ws + OFF_FBIG);
    float* sums = (float*)(ws + OFF_SUMS);
    int*   idx  = (int*)(ws + OFF_IDX);
    float* pre  = (float*)(ws + OFF_PRE);
    float* sqa  = (float*)(ws + OFF_SQ);   // aliases pre; consumed before conv

    k_prep<<<658, 256, 0, stream>>>(x, F, pos, xT, Fb, sums, sqa);
    k_knn<<<2048, 256, 0, stream>>>(pos, sqa, idx);
    k_conv<<<512, 256, 0, stream>>>(xT, Fb, idx, pre, sums);
    k_bn<<<512, 256, 0, stream>>>(pre, sums, gamma, beta, out);
}

// Round 9
// 261.721 us; speedup vs baseline: 1.0483x; 1.0483x over previous
//
#include <hip/hip_runtime.h>
#include <hip/hip_bf16.h>

// Problem constants (B=4, C=64, N=8192, K=16, D=64)
#define NPTS 8192
#define NQ   32768      // B*N
#define KNN  16
#define SCAP 112        // survivor cap per query (expected ~25-50)

// ws layout (bytes)
#define OFF_XT   0                      // B*N*C f32 = 8 MB  (x transposed to (B,N,C))
#define OFF_FBIG (8*1024*1024)          // 17*64*64 f32 = 278528 B (F with appended -sum(F))
#define OFF_SUMS (OFF_FBIG + 278528)    // 128 f32 (sum, sumsq per channel)
#define OFF_IDX  (OFF_SUMS + 512)       // B*N*16 int32 = 2 MB
#define OFF_PRE  (OFF_IDX + 2*1024*1024)// B*N*64 f32 = 8 MB (pre-BN output, (B*N, D))
// sq array (B*N f32 = 128 KB) ALIASES the start of PRE: k_prep writes it,
// k_knn consumes it, then k_conv overwrites PRE — stream-ordered, safe.
#define OFF_SQ   OFF_PRE

typedef float f2 __attribute__((ext_vector_type(2)));
#define SP2(v) ((f2){(v), (v)})

// Reference fp32 key — numpy execution model (verified R6, absmax 0.0156):
//   sq[m]   = (x*x + y*y) + z*z                  -- non-fused (np.sum(pos*pos))
//   inner   = fma(z,z', fma(y,y', rnd(x*x')))    -- einsum AVX2 axpy FMA chain
//   negd    = ((2*inner) - sq_n) - sq_m          -- elementwise, left-to-right
__device__ __forceinline__ float sq3(float x, float y, float z) {
    #pragma clang fp contract(off)
    float xx = x * x;
    float yy = y * y;
    float zz = z * z;
    return (xx + yy) + zz;
}
__device__ __forceinline__ float negd2(float qx, float qy, float qz, float sqn,
                                       float mx, float my, float mz, float sqm) {
    #pragma clang fp contract(off)
    float p0 = qx * mx;
    float inn = __builtin_fmaf(qz, mz, __builtin_fmaf(qy, my, p0));
    float t = 2.0f * inn;
    float u = t - sqn;
    return u - sqm;
}
// Filter margin: cheap fused key c~ = 2<q,m> - sqm differs from (exact key +
// sqn) by <= ~1e-4. 2e-3 is 20x conservative; two eps-steps cover tau-side
// and member-side error -> survivor set provably supersets the true top-16.
#define KEY_EPS2 2.0e-3f

// uniform-load helper: value is wave-uniform -> pin to SGPR
__device__ __forceinline__ float rfl(float v) {
    return __uint_as_float(__builtin_amdgcn_readfirstlane(__float_as_uint(v)));
}

// ---------------- K0: merged prep (transpose x | Fbig | zero sums | sq) ------
// blocks 0..511: transpose x. 512..527: Fbig j. 528: Fbig[16]=-sum. 529: zero
// sums. 530..657: sq per point (exact reference rounding).
__global__ __launch_bounds__(256) void k_prep(const float* __restrict__ x,
                                              const float* __restrict__ F,
                                              const float* __restrict__ pos,
                                              float* __restrict__ xT,
                                              float* __restrict__ Fb,
                                              float* __restrict__ sums,
                                              float* __restrict__ sqa) {
    int bid = blockIdx.x;
    if (bid < 512) {
        __shared__ float tile[64][65];
        int lane = threadIdx.x & 63, wid = threadIdx.x >> 6;
        int b = bid >> 7, nt = bid & 127;
        int n0 = nt * 64;
        for (int rr = 0; rr < 16; ++rr) {
            int c = wid * 16 + rr;
            tile[c][lane] = x[((size_t)b * 64 + c) * NPTS + n0 + lane];
        }
        __syncthreads();
        for (int rr = 0; rr < 16; ++rr) {
            int r = wid * 16 + rr;
            xT[((size_t)(b * NPTS + n0 + r)) * 64 + lane] = tile[lane][r];
        }
    } else if (bid < 528) {
        int j = bid - 512;
        for (int e = threadIdx.x; e < 4096; e += 256)
            Fb[j * 4096 + e] = F[j * 4096 + e];
    } else if (bid == 528) {
        for (int e = threadIdx.x; e < 4096; e += 256) {
            float s = 0.f;
            for (int k = 0; k < 16; ++k) s += F[k * 4096 + e];
            Fb[16 * 4096 + e] = -s;
        }
    } else if (bid == 529) {
        if (threadIdx.x < 128) sums[threadIdx.x] = 0.f;
    } else {
        int g = (bid - 530) * 256 + threadIdx.x;   // 0..NQ-1
        int b = g >> 13, n = g & (NPTS - 1);
        const float* pb = pos + (size_t)b * 3 * NPTS;
        sqa[g] = sq3(pb[n], pb[NPTS + n], pb[2 * NPTS + n]);
    }
}

// Radix-ballot select: thr[i] = (16th largest of 64 lane values lm[i]) - eps.
// Exact 16th-of-lane-maxima over the FULL candidate set (R3 lesson: prefix
// thresholds explode survivor counts 5-8x — never again).
__device__ __forceinline__ void sel16(const float* lm, float* thr) {
    unsigned up[4], pfx[4];
    #pragma unroll
    for (int i = 0; i < 4; ++i) {
        unsigned s = __float_as_uint(lm[i]);
        up[i]  = s ^ ((unsigned)((int)s >> 31) | 0x80000000u);
        pfx[i] = 0u;
    }
    for (int bit = 31; bit >= 0; --bit) {
        unsigned bmask = 1u << bit;
        #pragma unroll
        for (int i = 0; i < 4; ++i) {
            unsigned trial = pfx[i] | bmask;
            unsigned long long m = __ballot(up[i] >= trial);
            if (__popcll(m) >= 16) pfx[i] = trial;
        }
    }
    #pragma unroll
    for (int i = 0; i < 4; ++i) {
        unsigned p = pfx[i];
        unsigned sbits = (p & 0x80000000u) ? (p ^ 0x80000000u) : ~p;
        thr[i] = __uint_as_float(sbits) - KEY_EPS2;
    }
}

// ---------------- K1: kNN, coop split + query-PAIR packed fp32 (R26) ---------
// R24 base (wave w scans chunk [w*2048,(w+1)*2048) for all 16 block queries;
// spill-free; 107 us). R8 post-mortem: pk DID cut VALU (73->50% busy) but the
// two-group sweep DOUBLED loads -> net regression. R26 packs two DIFFERENT
// queries per f2 half (qx[p] = {2x_{2p}, 2x_{2p+1}}), splatting the CANDIDATE
// scalar instead ((f2){X.x,X.x} -> 1 mov/op_sel per cand) -> all 16 queries in
// ONE sweep, load count identical to R7, scan issue slots ~0.55x (272->144
// pass1, 256->176 pass2 per 4-cands). Per-half pk fma/max are IEEE-identical
// to the scalar chain -> same keys/thresholds/survivors/output. 48 VGPR coeff
// pairs + lm2 16 -> ~100 VGPR < 128 @ (256,4); all arrays compile-time-indexed.
__global__ __launch_bounds__(256, 4) void k_knn(const float* __restrict__ pos,
                                                const float* __restrict__ sqa,
                                                int* __restrict__ idxo) {
    __shared__ int   cnt[16];
    __shared__ int   outI[16][16];
    __shared__ float thrs[16];
    __shared__ union {
        float lm[16][256];                                  // pass-1 partials
        struct {                                            // pass-2 onward
            unsigned short sidx[16][SCAP];
            float          skey[16][SCAP];
        } ab;
    } sh;
    int t = threadIdx.x, lane = t & 63, wid = t >> 6;
    int qblk = blockIdx.x * 16;               // 16 queries per block, same batch
    int b = qblk >> 13;
    const float* px = pos + (size_t)b * 3 * NPTS;
    const float* py = px + NPTS;
    const float* pz = py + NPTS;
    const float* sb = sqa + (size_t)b * NPTS;
    int qn = qblk & (NPTS - 1);               // block's first query (in-batch)

    if (lane < 4) cnt[wid * 4 + lane] = 0;
    if (lane < 16) {
        #pragma unroll
        for (int i = 0; i < 4; ++i) outI[wid * 4 + i][lane] = qn + wid * 4 + i;
    }

    int base = wid * 2048;

    // query-pair coefficients: qx[p] = {2*x(2p), 2*x(2p+1)} etc.  48 VGPRs.
    f2 qx[8], qy[8], qz[8];
    #pragma unroll
    for (int p = 0; p < 8; ++p) {
        qx[p] = (f2){2.0f * px[qn + 2*p], 2.0f * px[qn + 2*p + 1]};
        qy[p] = (f2){2.0f * py[qn + 2*p], 2.0f * py[qn + 2*p + 1]};
        qz[p] = (f2){2.0f * pz[qn + 2*p], 2.0f * pz[qn + 2*p + 1]};
    }

    // pass 1: lane-max per query-pair (pk_fma + pk_max), single sweep
    f2 lm2[8];
    #pragma unroll
    for (int p = 0; p < 8; ++p) lm2[p] = (f2){-3.4e38f, -3.4e38f};
    for (int it = 0; it < 8; ++it) {
        int m = base + it * 256 + lane * 4;
        float4 X = *(const float4*)(px + m);
        float4 Y = *(const float4*)(py + m);
        float4 Z = *(const float4*)(pz + m);
        float4 S = *(const float4*)(sb + m);
        #define P1_CAND(CX, CY, CZ, CS)                                        \
        {                                                                      \
            f2 cx = SP2(CX), cy = SP2(CY), cz = SP2(CZ), cs = SP2(-(CS));      \
            _Pragma("unroll")                                                  \
            for (int p = 0; p < 8; ++p) {                                      \
                f2 kk = __builtin_elementwise_fma(qx[p], cx,                   \
                        __builtin_elementwise_fma(qy[p], cy,                   \
                        __builtin_elementwise_fma(qz[p], cz, cs)));            \
                lm2[p] = __builtin_elementwise_max(lm2[p], kk);                \
            }                                                                  \
        }
        P1_CAND(X.x, Y.x, Z.x, S.x)
        P1_CAND(X.y, Y.y, Z.y, S.y)
        P1_CAND(X.z, Y.z, Z.z, S.z)
        P1_CAND(X.w, Y.w, Z.w, S.w)
        #undef P1_CAND
    }
    // publish partials (compile-time indices only)
    #pragma unroll
    for (int p = 0; p < 8; ++p) {
        sh.lm[2*p    ][wid * 64 + lane] = lm2[p].x;
        sh.lm[2*p + 1][wid * 64 + lane] = lm2[p].y;
    }
    __syncthreads();

    // wave w: combine 4 waves' partials for queries 4w..4w+3, sel16 -> thrs
    {
        float comb[4];
        #pragma unroll
        for (int j = 0; j < 4; ++j) {
            int i = wid * 4 + j;
            float c0 = sh.lm[i][lane];
            float c1 = sh.lm[i][64 + lane];
            float c2 = sh.lm[i][128 + lane];
            float c3 = sh.lm[i][192 + lane];
            comb[j] = fmaxf(fmaxf(c0, c1), fmaxf(c2, c3));
        }
        float thr4[4];
        sel16(comb, thr4);
        // thr4 is lane-invariant (built from wave-uniform ballots); publish
        // via lane 0 with a fully-unrolled loop (NO runtime index into thr4).
        if (lane == 0) {
            #pragma unroll
            for (int j = 0; j < 4; ++j) thrs[wid * 4 + j] = thr4[j];
        }
    }
    __syncthreads();
    // block-uniform thresholds -> SGPRs (VOPC reads SGPR src)
    float thr[16];
    #pragma unroll
    for (int i = 0; i < 16; ++i) thr[i] = rfl(thrs[i]);

    // pass 2: single sweep, pk keys per query-pair, scalar cmp vs SGPR thr
    for (int it = 0; it < 8; ++it) {
        int m = base + it * 256 + lane * 4;
        float4 X = *(const float4*)(px + m);
        float4 Y = *(const float4*)(py + m);
        float4 Z = *(const float4*)(pz + m);
        float4 S = *(const float4*)(sb + m);
        #define P2_CAND(CX, CY, CZ, CS, MI)                                    \
        {                                                                      \
            f2 cx = SP2(CX), cy = SP2(CY), cz = SP2(CZ), cs = SP2(-(CS));      \
            _Pragma("unroll")                                                  \
            for (int p = 0; p < 8; ++p) {                                      \
                f2 kk = __builtin_elementwise_fma(qx[p], cx,                   \
                        __builtin_elementwise_fma(qy[p], cy,                   \
                        __builtin_elementwise_fma(qz[p], cz, cs)));            \
                if (kk.x >= thr[2*p]) {                                        \
                    int s_ = atomicAdd(&cnt[2*p], 1);                          \
                    if (s_ < SCAP) sh.ab.sidx[2*p][s_] = (unsigned short)(MI); \
                }                                                              \
                if (kk.y >= thr[2*p+1]) {                                      \
                    int s_ = atomicAdd(&cnt[2*p+1], 1);                        \
                    if (s_ < SCAP) sh.ab.sidx[2*p+1][s_] = (unsigned short)(MI);\
                }                                                              \
            }                                                                  \
        }
        P2_CAND(X.x, Y.x, Z.x, S.x, m)
        P2_CAND(X.y, Y.y, Z.y, S.y, m + 1)
        P2_CAND(X.z, Y.z, Z.z, S.z, m + 2)
        P2_CAND(X.w, Y.w, Z.w, S.w, m + 3)
        #undef P2_CAND
    }
    __syncthreads();

    // phase A: exact reference key per survivor (wave w: queries 4w..4w+3).
    // Query coords re-loaded from global (L1-hot) — runtime lq only indexes
    // MEMORY, never register arrays (R5 scratch lesson).
    #pragma unroll 1
    for (int i = 0; i < 4; ++i) {
        int lq = wid * 4 + i;
        float qxx = px[qn + lq], qyy = py[qn + lq], qzz = pz[qn + lq];
        float sqn = sb[qn + lq];
        int S = cnt[lq]; if (S > SCAP) S = SCAP;
        for (int p = lane; p < S; p += 64) {
            int m = sh.ab.sidx[lq][p];
            sh.ab.skey[lq][p] = negd2(qxx, qyy, qzz, sqn,
                                      px[m], py[m], pz[m], sb[m]);
        }
    }
    __syncthreads();

    // phase B: exact rerank; ties -> lower index (lax.top_k semantics)
    #pragma unroll 1
    for (int i = 0; i < 4; ++i) {
        int lq = wid * 4 + i;
        int S = cnt[lq]; if (S > SCAP) S = SCAP;
        for (int p = lane; p < S; p += 64) {
            int m = sh.ab.sidx[lq][p];
            float km = sh.ab.skey[lq][p];
            int rank = 0;
            for (int j = 0; j < S; ++j) {
                float kj = sh.ab.skey[lq][j];
                int ij = sh.ab.sidx[lq][j];
                if (kj > km || (kj == km && ij < m)) rank++;
            }
            if (rank < KNN) outI[lq][rank] = m;
        }
    }
    __syncthreads();
    // write out 16 queries x 16 ranks
    {
        int lq = t >> 4;
        idxo[(size_t)(qblk + lq) * KNN + (t & 15)] = outI[lq][t & 15];
    }
}

// ---------------- K2: gather + GEMM + fused BN-stats epilogue ----------------
// outp[q][d] = sum_{j=0..16} sum_c xT[nbr_j(q)][c] * Fbig[j][c][d]
// Tile: 64 q x 64 d, 256 threads, 4x4 micro (R9/R13 proven). Epilogue computes
// block-partial per-channel sum/sumsq from live accumulators (reusing Bt).
// R10/R14 both showed 128-thread variants regress (occupancy cliff).
#define CPAD 68
__global__ __launch_bounds__(256) void k_conv(const float* __restrict__ xT,
                                              const float* __restrict__ Fb,
                                              const int* __restrict__ idx,
                                              float* __restrict__ outp,
                                              float* __restrict__ sums) {
    __shared__ float At[64][CPAD];
    __shared__ float Bt[64 * 64];
    int t = threadIdx.x;
    int q0 = blockIdx.x * 64;                 // tile base (same batch: 8192%64==0)
    int bbase = q0 & ~(NPTS - 1);             // batch row offset in xT
    int qi0 = (t >> 4) * 4;                   // query sub-block 0..60
    int dj0 = (t & 15) * 4;                   // d sub-block 0..60
    int r = t & 63;                           // gather row
    int s = t >> 6;                           // 16-float segment

    float acc[4][4];
    #pragma unroll
    for (int a = 0; a < 4; ++a)
        #pragma unroll
        for (int bb = 0; bb < 4; ++bb) acc[a][bb] = 0.f;

    for (int j = 0; j < 17; ++j) {
        // ---- stage A: gather 64 neighbor rows, store transposed ----
        {
            int qg = q0 + r;
            int nbr = (j < 16) ? (idx[(size_t)qg * KNN + j] & (NPTS - 1))
                               : (qg & (NPTS - 1));
            const float* src = xT + ((size_t)(bbase + nbr) * 64 + s * 16);
            float4 v0 = *(const float4*)(src);
            float4 v1 = *(const float4*)(src + 4);
            float4 v2 = *(const float4*)(src + 8);
            float4 v3 = *(const float4*)(src + 12);
            int c0 = s * 16;
            At[c0+ 0][r] = v0.x; At[c0+ 1][r] = v0.y; At[c0+ 2][r] = v0.z; At[c0+ 3][r] = v0.w;
            At[c0+ 4][r] = v1.x; At[c0+ 5][r] = v1.y; At[c0+ 6][r] = v1.z; At[c0+ 7][r] = v1.w;
            At[c0+ 8][r] = v2.x; At[c0+ 9][r] = v2.y; At[c0+10][r] = v2.z; At[c0+11][r] = v2.w;
            At[c0+12][r] = v3.x; At[c0+13][r] = v3.y; At[c0+14][r] = v3.z; At[c0+15][r] = v3.w;
        }
        // ---- stage B: copy F[j] (4096 floats) ----
        {
            const float* fj = Fb + j * 4096;
            #pragma unroll
            for (int u = 0; u < 4; ++u) {
                int e = u * 1024 + t * 4;
                *(float4*)&Bt[e] = *(const float4*)(fj + e);
            }
        }
        __syncthreads();
        // ---- compute: 64 k-steps ----
        #pragma unroll 8
        for (int k = 0; k < 64; ++k) {
            float4 av = *(const float4*)&At[k][qi0];
            float4 bv = *(const float4*)&Bt[k * 64 + dj0];
            acc[0][0] = fmaf(av.x, bv.x, acc[0][0]);
            acc[0][1] = fmaf(av.x, bv.y, acc[0][1]);
            acc[0][2] = fmaf(av.x, bv.z, acc[0][2]);
            acc[0][3] = fmaf(av.x, bv.w, acc[0][3]);
            acc[1][0] = fmaf(av.y, bv.x, acc[1][0]);
            acc[1][1] = fmaf(av.y, bv.y, acc[1][1]);
            acc[1][2] = fmaf(av.y, bv.z, acc[1][2]);
            acc[1][3] = fmaf(av.y, bv.w, acc[1][3]);
            acc[2][0] = fmaf(av.z, bv.x, acc[2][0]);
            acc[2][1] = fmaf(av.z, bv.y, acc[2][1]);
            acc[2][2] = fmaf(av.z, bv.z, acc[2][2]);
            acc[2][3] = fmaf(av.z, bv.w, acc[2][3]);
            acc[3][0] = fmaf(av.w, bv.x, acc[3][0]);
            acc[3][1] = fmaf(av.w, bv.y, acc[3][1]);
            acc[3][2] = fmaf(av.w, bv.z, acc[3][2]);
            acc[3][3] = fmaf(av.w, bv.w, acc[3][3]);
        }
        __syncthreads();
    }
    // ---- epilogue 1: store outputs ----
    #pragma unroll
    for (int qi = 0; qi < 4; ++qi) {
        float4 o = make_float4(acc[qi][0], acc[qi][1], acc[qi][2], acc[qi][3]);
        *(float4*)(outp + (size_t)(q0 + qi0 + qi) * 64 + dj0) = o;
    }
    // ---- epilogue 2: fused BN stats (reuse Bt: P=sum, P2=sumsq; 16 q-groups) ----
    {
        float* P  = Bt;          // [16][64]
        float* P2 = Bt + 1024;   // [16][64]
        int g = t >> 4;          // q-group 0..15
        #pragma unroll
        for (int dd = 0; dd < 4; ++dd) {
            float sv = ((acc[0][dd] + acc[1][dd]) + acc[2][dd]) + acc[3][dd];
            float qv = fmaf(acc[3][dd], acc[3][dd],
                       fmaf(acc[2][dd], acc[2][dd],
                       fmaf(acc[1][dd], acc[1][dd], acc[0][dd] * acc[0][dd])));
            P [g * 64 + dj0 + dd] = sv;
            P2[g * 64 + dj0 + dd] = qv;
        }
        __syncthreads();
        if (t < 64) {
            float a = 0.f, b2 = 0.f;
            #pragma unroll
            for (int gg = 0; gg < 16; ++gg) {
                a  += P [gg * 64 + t];
                b2 += P2[gg * 64 + t];
            }
            atomicAdd(&sums[t], a);
            atomicAdd(&sums[64 + t], b2);
        }
    }
}

// ---------------- K3: BN + transpose (B,N,D) -> (B,D,N) ----------------
__global__ __launch_bounds__(256) void k_bn(const float* __restrict__ outp,
                                            const float* __restrict__ sums,
                                            const float* __restrict__ gamma,
                                            const float* __restrict__ beta,
                                            float* __restrict__ out) {
    __shared__ float tile[64][65];
    __shared__ float sa[64], sb[64];
    int lane = threadIdx.x & 63, wid = threadIdx.x >> 6;
    int b = blockIdx.x >> 7, nt = blockIdx.x & 127;
    int n0 = nt * 64;
    if (threadIdx.x < 64) {
        const float inv = 1.f / 32768.f;
        float mean = sums[threadIdx.x] * inv;
        float var = sums[64 + threadIdx.x] * inv - mean * mean;
        float rs = rsqrtf(var + 1e-5f);
        float a = rs * gamma[threadIdx.x];
        sa[threadIdx.x] = a;
        sb[threadIdx.x] = beta[threadIdx.x] - mean * a;
    }
    for (int rr = 0; rr < 16; ++rr) {
        int r = wid * 16 + rr;
        tile[r][lane] = outp[((size_t)(b * NPTS + n0 + r)) * 64 + lane];
    }
    __syncthreads();
    for (int rr = 0; rr < 16; ++rr) {
        int dr = wid * 16 + rr;
        out[((size_t)b * 64 + dr) * NPTS + n0 + lane] =
            fmaf(tile[lane][dr], sa[dr], sb[dr]);
    }
}

extern "C" void kernel_launch(void* const* d_in, const int* in_sizes, int n_in,
                              void* d_out, int out_size, void* d_ws, size_t ws_size,
                              hipStream_t stream) {
    (void)in_sizes; (void)n_in; (void)out_size; (void)ws_size;
    const float* x     = (const float*)d_in[0];  // (4,64,8192)
    const float* pos   = (const float*)d_in[1];  // (4,3,8192)
    const float* F     = (const float*)d_in[2];  // (16,64,64)
    const float* gamma = (const float*)d_in[3];  // (64,)
    const float* beta  = (const float*)d_in[4];  // (64,)
    float* out = (float*)d_out;                  // (4,64,8192)

    char* ws = (char*)d_ws;
    float* xT   = (float*)(ws + OFF_XT);
    float* Fb   = (float*)(ws + OFF_FBIG);
    float* sums = (float*)(ws + OFF_SUMS);
    int*   idx  = (int*)(ws + OFF_IDX);
    float* pre  = (float*)(ws + OFF_PRE);
    float* sqa  = (float*)(ws + OFF_SQ);   // aliases pre; consumed before conv

    k_prep<<<658, 256, 0, stream>>>(x, F, pos, xT, Fb, sums, sqa);
    k_knn<<<2048, 256, 0, stream>>>(pos, sqa, idx);
    k_conv<<<512, 256, 0, stream>>>(xT, Fb, idx, pre, sums);
    k_bn<<<512, 256, 0, stream>>>(pre, sums, gamma, beta, out);
}

// Round 10
// 256.812 us; speedup vs baseline: 1.0684x; 1.0191x over previous
//
#include <hip/hip_runtime.h>
#include <hip/hip_bf16.h>

// Problem constants (B=4, C=64, N=8192, K=16, D=64)
#define NPTS 8192
#define NQ   32768      // B*N
#define KNN  16
#define SCAP 112        // survivor cap per query (expected ~25-50)

// ws layout (bytes)
#define OFF_XT   0                      // B*N*C f32 = 8 MB  (x transposed to (B,N,C))
#define OFF_FBIG (8*1024*1024)          // 17*64*64 f32 = 278528 B (F with appended -sum(F))
#define OFF_SUMS (OFF_FBIG + 278528)    // 128 f32 (sum, sumsq per channel)
#define OFF_IDX  (OFF_SUMS + 512)       // B*N*16 int32 = 2 MB
#define OFF_PRE  (OFF_IDX + 2*1024*1024)// B*N*64 f32 = 8 MB (pre-BN output, (B*N, D))
// sq array (B*N f32 = 128 KB) ALIASES the start of PRE: k_prep writes it,
// k_knn consumes it, then k_conv overwrites PRE — stream-ordered, safe.
#define OFF_SQ   OFF_PRE

// Reference fp32 key — numpy execution model (verified R6, absmax 0.0156):
//   sq[m]   = (x*x + y*y) + z*z                  -- non-fused (np.sum(pos*pos))
//   inner   = fma(z,z', fma(y,y', rnd(x*x')))    -- einsum AVX2 axpy FMA chain
//   negd    = ((2*inner) - sq_n) - sq_m          -- elementwise, left-to-right
__device__ __forceinline__ float sq3(float x, float y, float z) {
    #pragma clang fp contract(off)
    float xx = x * x;
    float yy = y * y;
    float zz = z * z;
    return (xx + yy) + zz;
}
__device__ __forceinline__ float negd2(float qx, float qy, float qz, float sqn,
                                       float mx, float my, float mz, float sqm) {
    #pragma clang fp contract(off)
    float p0 = qx * mx;
    float inn = __builtin_fmaf(qz, mz, __builtin_fmaf(qy, my, p0));
    float t = 2.0f * inn;
    float u = t - sqn;
    return u - sqm;
}
// Filter margin: cheap fused key c~ = 2<q,m> - sqm differs from (exact key +
// sqn) by <= ~1e-4. 2e-3 is 20x conservative; two eps-steps cover tau-side
// and member-side error -> survivor set provably supersets the true top-16.
#define KEY_EPS2 2.0e-3f

// uniform-load helper: value is wave-uniform -> pin to SGPR
__device__ __forceinline__ float rfl(float v) {
    return __uint_as_float(__builtin_amdgcn_readfirstlane(__float_as_uint(v)));
}

// ---------------- K0: merged prep (transpose x | Fbig | zero sums | sq) ------
// blocks 0..511: transpose x. 512..527: Fbig j. 528: Fbig[16]=-sum. 529: zero
// sums. 530..657: sq per point (exact reference rounding).
__global__ __launch_bounds__(256) void k_prep(const float* __restrict__ x,
                                              const float* __restrict__ F,
                                              const float* __restrict__ pos,
                                              float* __restrict__ xT,
                                              float* __restrict__ Fb,
                                              float* __restrict__ sums,
                                              float* __restrict__ sqa) {
    int bid = blockIdx.x;
    if (bid < 512) {
        __shared__ float tile[64][65];
        int lane = threadIdx.x & 63, wid = threadIdx.x >> 6;
        int b = bid >> 7, nt = bid & 127;
        int n0 = nt * 64;
        for (int rr = 0; rr < 16; ++rr) {
            int c = wid * 16 + rr;
            tile[c][lane] = x[((size_t)b * 64 + c) * NPTS + n0 + lane];
        }
        __syncthreads();
        for (int rr = 0; rr < 16; ++rr) {
            int r = wid * 16 + rr;
            xT[((size_t)(b * NPTS + n0 + r)) * 64 + lane] = tile[lane][r];
        }
    } else if (bid < 528) {
        int j = bid - 512;
        for (int e = threadIdx.x; e < 4096; e += 256)
            Fb[j * 4096 + e] = F[j * 4096 + e];
    } else if (bid == 528) {
        for (int e = threadIdx.x; e < 4096; e += 256) {
            float s = 0.f;
            for (int k = 0; k < 16; ++k) s += F[k * 4096 + e];
            Fb[16 * 4096 + e] = -s;
        }
    } else if (bid == 529) {
        if (threadIdx.x < 128) sums[threadIdx.x] = 0.f;
    } else {
        int g = (bid - 530) * 256 + threadIdx.x;   // 0..NQ-1
        int b = g >> 13, n = g & (NPTS - 1);
        const float* pb = pos + (size_t)b * 3 * NPTS;
        sqa[g] = sq3(pb[n], pb[NPTS + n], pb[2 * NPTS + n]);
    }
}

// Radix-ballot select: thr[i] = (16th largest of 64 lane values lm[i]) - eps.
// Exact 16th-of-lane-maxima over the FULL candidate set (R3 lesson: prefix
// thresholds explode survivor counts 5-8x — never again).
__device__ __forceinline__ void sel16(const float* lm, float* thr) {
    unsigned up[4], pfx[4];
    #pragma unroll
    for (int i = 0; i < 4; ++i) {
        unsigned s = __float_as_uint(lm[i]);
        up[i]  = s ^ ((unsigned)((int)s >> 31) | 0x80000000u);
        pfx[i] = 0u;
    }
    for (int bit = 31; bit >= 0; --bit) {
        unsigned bmask = 1u << bit;
        #pragma unroll
        for (int i = 0; i < 4; ++i) {
            unsigned trial = pfx[i] | bmask;
            unsigned long long m = __ballot(up[i] >= trial);
            if (__popcll(m) >= 16) pfx[i] = trial;
        }
    }
    #pragma unroll
    for (int i = 0; i < 4; ++i) {
        unsigned p = pfx[i];
        unsigned sbits = (p & 0x80000000u) ? (p ^ 0x80000000u) : ~p;
        thr[i] = __uint_as_float(sbits) - KEY_EPS2;
    }
}

// ---------------- K1: kNN, block-cooperative candidate split (R24, banked) ---
// R24 verbatim (107.4 us, VALUBusy 73% == scalar issue floor). R25/R26 pk
// variants cut VALU cycles (78->61 us) but REGRESSED duration (125/115.5):
// non-VALU time grew (splat movs, pk_max serial chains, occupancy slip) and
// fp32 pk buys slots, not FLOPs (157.3 TF peak == plain v_fma rate). Scalar
// scan is the plateau for this structure — pk on k_knn is dead.
__global__ __launch_bounds__(256, 4) void k_knn(const float* __restrict__ pos,
                                                const float* __restrict__ sqa,
                                                int* __restrict__ idxo) {
    __shared__ int   cnt[16];
    __shared__ int   outI[16][16];
    __shared__ float thrs[16];
    __shared__ union {
        float lm[16][256];                                  // pass-1 partials
        struct {                                            // pass-2 onward
            unsigned short sidx[16][SCAP];
            float          skey[16][SCAP];
        } ab;
    } sh;
    int t = threadIdx.x, lane = t & 63, wid = t >> 6;
    int qblk = blockIdx.x * 16;               // 16 queries per block, same batch
    int b = qblk >> 13;
    const float* px = pos + (size_t)b * 3 * NPTS;
    const float* py = px + NPTS;
    const float* pz = py + NPTS;
    const float* sb = sqa + (size_t)b * NPTS;
    int qn = qblk & (NPTS - 1);               // block's first query (in-batch)

    // all 16 query coefficients, wave-uniform -> SGPRs (compile-time idx only!)
    float tqx[16], tqy[16], tqz[16];
    #pragma unroll
    for (int i = 0; i < 16; ++i) {
        tqx[i] = rfl(2.0f * px[qn + i]);
        tqy[i] = rfl(2.0f * py[qn + i]);
        tqz[i] = rfl(2.0f * pz[qn + i]);
    }
    if (lane < 4) cnt[wid * 4 + lane] = 0;
    if (lane < 16) {
        #pragma unroll
        for (int i = 0; i < 4; ++i) outI[wid * 4 + i][lane] = qn + wid * 4 + i;
    }

    // pass 1: this wave's 2048-cand chunk, lane-max for all 16 queries
    float lm[16];
    #pragma unroll
    for (int i = 0; i < 16; ++i) lm[i] = -3.4e38f;
    int base = wid * 2048;
    for (int it = 0; it < 8; ++it) {
        int m = base + it * 256 + lane * 4;
        float4 X = *(const float4*)(px + m);
        float4 Y = *(const float4*)(py + m);
        float4 Z = *(const float4*)(pz + m);
        float4 S = *(const float4*)(sb + m);
        #pragma unroll
        for (int i = 0; i < 16; ++i) {
            float a0 = __builtin_fmaf(tqx[i], X.x, __builtin_fmaf(tqy[i], Y.x, __builtin_fmaf(tqz[i], Z.x, -S.x)));
            float a1 = __builtin_fmaf(tqx[i], X.y, __builtin_fmaf(tqy[i], Y.y, __builtin_fmaf(tqz[i], Z.y, -S.y)));
            float a2 = __builtin_fmaf(tqx[i], X.z, __builtin_fmaf(tqy[i], Y.z, __builtin_fmaf(tqz[i], Z.z, -S.z)));
            float a3 = __builtin_fmaf(tqx[i], X.w, __builtin_fmaf(tqy[i], Y.w, __builtin_fmaf(tqz[i], Z.w, -S.w)));
            float m012 = fmaxf(fmaxf(a0, a1), a2);
            lm[i] = fmaxf(fmaxf(m012, a3), lm[i]);
        }
    }
    // publish partials
    #pragma unroll
    for (int i = 0; i < 16; ++i) sh.lm[i][wid * 64 + lane] = lm[i];
    __syncthreads();

    // wave w: combine 4 waves' partials for queries 4w..4w+3, sel16 -> thrs
    {
        float comb[4];
        #pragma unroll
        for (int j = 0; j < 4; ++j) {
            int i = wid * 4 + j;
            float c0 = sh.lm[i][lane];
            float c1 = sh.lm[i][64 + lane];
            float c2 = sh.lm[i][128 + lane];
            float c3 = sh.lm[i][192 + lane];
            comb[j] = fmaxf(fmaxf(c0, c1), fmaxf(c2, c3));
        }
        float thr4[4];
        sel16(comb, thr4);
        // thr4 is lane-invariant (built from wave-uniform ballots); publish
        // via lane 0 with a fully-unrolled loop (NO runtime index into thr4).
        if (lane == 0) {
            #pragma unroll
            for (int j = 0; j < 4; ++j) thrs[wid * 4 + j] = thr4[j];
        }
    }
    __syncthreads();
    // block-uniform thresholds -> SGPRs (VOPC reads SGPR src)
    float thr[16];
    #pragma unroll
    for (int i = 0; i < 16; ++i) thr[i] = rfl(thrs[i]);

    // pass 2: re-scan this wave's chunk vs all 16 thresholds; push survivors
    for (int it = 0; it < 8; ++it) {
        int m = base + it * 256 + lane * 4;
        float4 X = *(const float4*)(px + m);
        float4 Y = *(const float4*)(py + m);
        float4 Z = *(const float4*)(pz + m);
        float4 S = *(const float4*)(sb + m);
        #pragma unroll
        for (int i = 0; i < 16; ++i) {
            float a0 = __builtin_fmaf(tqx[i], X.x, __builtin_fmaf(tqy[i], Y.x, __builtin_fmaf(tqz[i], Z.x, -S.x)));
            float a1 = __builtin_fmaf(tqx[i], X.y, __builtin_fmaf(tqy[i], Y.y, __builtin_fmaf(tqz[i], Z.y, -S.y)));
            float a2 = __builtin_fmaf(tqx[i], X.z, __builtin_fmaf(tqy[i], Y.z, __builtin_fmaf(tqz[i], Z.z, -S.z)));
            float a3 = __builtin_fmaf(tqx[i], X.w, __builtin_fmaf(tqy[i], Y.w, __builtin_fmaf(tqz[i], Z.w, -S.w)));
            if (a0 >= thr[i]) { int s_ = atomicAdd(&cnt[i],1); if (s_<SCAP) sh.ab.sidx[i][s_] = (unsigned short)m; }
            if (a1 >= thr[i]) { int s_ = atomicAdd(&cnt[i],1); if (s_<SCAP) sh.ab.sidx[i][s_] = (unsigned short)(m+1); }
            if (a2 >= thr[i]) { int s_ = atomicAdd(&cnt[i],1); if (s_<SCAP) sh.ab.sidx[i][s_] = (unsigned short)(m+2); }
            if (a3 >= thr[i]) { int s_ = atomicAdd(&cnt[i],1); if (s_<SCAP) sh.ab.sidx[i][s_] = (unsigned short)(m+3); }
        }
    }
    __syncthreads();

    // phase A: exact reference key per survivor (wave w: queries 4w..4w+3).
    // Query coords re-loaded from global (L1-hot) — runtime lq only indexes
    // MEMORY, never register arrays (R5 scratch lesson).
    #pragma unroll 1
    for (int i = 0; i < 4; ++i) {
        int lq = wid * 4 + i;
        float qxx = px[qn + lq], qyy = py[qn + lq], qzz = pz[qn + lq];
        float sqn = sb[qn + lq];
        int S = cnt[lq]; if (S > SCAP) S = SCAP;
        for (int p = lane; p < S; p += 64) {
            int m = sh.ab.sidx[lq][p];
            sh.ab.skey[lq][p] = negd2(qxx, qyy, qzz, sqn,
                                      px[m], py[m], pz[m], sb[m]);
        }
    }
    __syncthreads();

    // phase B: exact rerank; ties -> lower index (lax.top_k semantics)
    #pragma unroll 1
    for (int i = 0; i < 4; ++i) {
        int lq = wid * 4 + i;
        int S = cnt[lq]; if (S > SCAP) S = SCAP;
        for (int p = lane; p < S; p += 64) {
            int m = sh.ab.sidx[lq][p];
            float km = sh.ab.skey[lq][p];
            int rank = 0;
            for (int j = 0; j < S; ++j) {
                float kj = sh.ab.skey[lq][j];
                int ij = sh.ab.sidx[lq][j];
                if (kj > km || (kj == km && ij < m)) rank++;
            }
            if (rank < KNN) outI[lq][rank] = m;
        }
    }
    __syncthreads();
    // write out 16 queries x 16 ranks
    {
        int lq = t >> 4;
        idxo[(size_t)(qblk + lq) * KNN + (t & 15)] = outI[lq][t & 15];
    }
}

// ---------------- K2: gather + GEMM + fused BN-stats epilogue (R27) ----------
// outp[q][d] = sum_{j=0..16} sum_c xT[nbr_j(q)][c] * Fbig[j][c][d]
// Tile: 64 q x 64 d, 256 threads, 4x4 micro (R9/R13 proven). R27: T14-style
// register prefetch. Old loop exposed the gather chain (idx -> scattered xT
// row, ~200-400 cyc L2) + 16 KB Fb copy between the two barriers every j.
// New order: {sync; LDS-write(j) from regs; sync; issue loads(j+1)->regs;
// compute(j)} — loads are in flight across the ~2000-cyc compute and the
// mandatory vmcnt(0) drain at the NEXT iteration's first __syncthreads lands
// after the data already arrived. Standard barriers, no races. +32 VGPR.
#define CPAD 68
__global__ __launch_bounds__(256) void k_conv(const float* __restrict__ xT,
                                              const float* __restrict__ Fb,
                                              const int* __restrict__ idx,
                                              float* __restrict__ outp,
                                              float* __restrict__ sums) {
    __shared__ float At[64][CPAD];
    __shared__ float Bt[64 * 64];
    int t = threadIdx.x;
    int q0 = blockIdx.x * 64;                 // tile base (same batch: 8192%64==0)
    int bbase = q0 & ~(NPTS - 1);             // batch row offset in xT
    int qi0 = (t >> 4) * 4;                   // query sub-block 0..60
    int dj0 = (t & 15) * 4;                   // d sub-block 0..60
    int r = t & 63;                           // gather row
    int s = t >> 6;                           // 16-float segment

    float acc[4][4];
    #pragma unroll
    for (int a = 0; a < 4; ++a)
        #pragma unroll
        for (int bb = 0; bb < 4; ++bb) acc[a][bb] = 0.f;

    // prefetch registers (scalar names, compile-time access only)
    float4 ga0, ga1, ga2, ga3;                // gathered A row segment
    float4 gb0, gb1, gb2, gb3;                // Fb[j] slice

    #define LOADJ(J)                                                           \
    {                                                                          \
        int qg = q0 + r;                                                       \
        int nbr = ((J) < 16) ? (idx[(size_t)qg * KNN + (J)] & (NPTS - 1))      \
                             : (qg & (NPTS - 1));                              \
        const float* src = xT + ((size_t)(bbase + nbr) * 64 + s * 16);         \
        ga0 = *(const float4*)(src);                                           \
        ga1 = *(const float4*)(src + 4);                                       \
        ga2 = *(const float4*)(src + 8);                                       \
        ga3 = *(const float4*)(src + 12);                                      \
        const float* fj = Fb + (J) * 4096;                                     \
        gb0 = *(const float4*)(fj +    0 + t * 4);                             \
        gb1 = *(const float4*)(fj + 1024 + t * 4);                            \
        gb2 = *(const float4*)(fj + 2048 + t * 4);                            \
        gb3 = *(const float4*)(fj + 3072 + t * 4);                            \
    }

    LOADJ(0);
    for (int j = 0; j < 17; ++j) {
        __syncthreads();   // all waves done reading LDS for j-1; prefetch arrived
        // ---- write staged regs to LDS ----
        {
            int c0 = s * 16;
            At[c0+ 0][r] = ga0.x; At[c0+ 1][r] = ga0.y; At[c0+ 2][r] = ga0.z; At[c0+ 3][r] = ga0.w;
            At[c0+ 4][r] = ga1.x; At[c0+ 5][r] = ga1.y; At[c0+ 6][r] = ga1.z; At[c0+ 7][r] = ga1.w;
            At[c0+ 8][r] = ga2.x; At[c0+ 9][r] = ga2.y; At[c0+10][r] = ga2.z; At[c0+11][r] = ga2.w;
            At[c0+12][r] = ga3.x; At[c0+13][r] = ga3.y; At[c0+14][r] = ga3.z; At[c0+15][r] = ga3.w;
            *(float4*)&Bt[   0 + t * 4] = gb0;
            *(float4*)&Bt[1024 + t * 4] = gb1;
            *(float4*)&Bt[2048 + t * 4] = gb2;
            *(float4*)&Bt[3072 + t * 4] = gb3;
        }
        __syncthreads();   // writes visible; nothing in flight -> drain is free
        if (j < 16) LOADJ(j + 1);   // issue next loads; hide under compute
        // ---- compute: 64 k-steps ----
        #pragma unroll 8
        for (int k = 0; k < 64; ++k) {
            float4 av = *(const float4*)&At[k][qi0];
            float4 bv = *(const float4*)&Bt[k * 64 + dj0];
            acc[0][0] = fmaf(av.x, bv.x, acc[0][0]);
            acc[0][1] = fmaf(av.x, bv.y, acc[0][1]);
            acc[0][2] = fmaf(av.x, bv.z, acc[0][2]);
            acc[0][3] = fmaf(av.x, bv.w, acc[0][3]);
            acc[1][0] = fmaf(av.y, bv.x, acc[1][0]);
            acc[1][1] = fmaf(av.y, bv.y, acc[1][1]);
            acc[1][2] = fmaf(av.y, bv.z, acc[1][2]);
            acc[1][3] = fmaf(av.y, bv.w, acc[1][3]);
            acc[2][0] = fmaf(av.z, bv.x, acc[2][0]);
            acc[2][1] = fmaf(av.z, bv.y, acc[2][1]);
            acc[2][2] = fmaf(av.z, bv.z, acc[2][2]);
            acc[2][3] = fmaf(av.z, bv.w, acc[2][3]);
            acc[3][0] = fmaf(av.w, bv.x, acc[3][0]);
            acc[3][1] = fmaf(av.w, bv.y, acc[3][1]);
            acc[3][2] = fmaf(av.w, bv.z, acc[3][2]);
            acc[3][3] = fmaf(av.w, bv.w, acc[3][3]);
        }
    }
    #undef LOADJ
    // ---- epilogue 1: store outputs ----
    #pragma unroll
    for (int qi = 0; qi < 4; ++qi) {
        float4 o = make_float4(acc[qi][0], acc[qi][1], acc[qi][2], acc[qi][3]);
        *(float4*)(outp + (size_t)(q0 + qi0 + qi) * 64 + dj0) = o;
    }
    // ---- epilogue 2: fused BN stats (reuse Bt: P=sum, P2=sumsq; 16 q-groups) ----
    {
        __syncthreads();         // compute done in all waves before Bt reuse
        float* P  = Bt;          // [16][64]
        float* P2 = Bt + 1024;   // [16][64]
        int g = t >> 4;          // q-group 0..15
        #pragma unroll
        for (int dd = 0; dd < 4; ++dd) {
            float sv = ((acc[0][dd] + acc[1][dd]) + acc[2][dd]) + acc[3][dd];
            float qv = fmaf(acc[3][dd], acc[3][dd],
                       fmaf(acc[2][dd], acc[2][dd],
                       fmaf(acc[1][dd], acc[1][dd], acc[0][dd] * acc[0][dd])));
            P [g * 64 + dj0 + dd] = sv;
            P2[g * 64 + dj0 + dd] = qv;
        }
        __syncthreads();
        if (t < 64) {
            float a = 0.f, b2 = 0.f;
            #pragma unroll
            for (int gg = 0; gg < 16; ++gg) {
                a  += P [gg * 64 + t];
                b2 += P2[gg * 64 + t];
            }
            atomicAdd(&sums[t], a);
            atomicAdd(&sums[64 + t], b2);
        }
    }
}

// ---------------- K3: BN + transpose (B,N,D) -> (B,D,N) ----------------
__global__ __launch_bounds__(256) void k_bn(const float* __restrict__ outp,
                                            const float* __restrict__ sums,
                                            const float* __restrict__ gamma,
                                            const float* __restrict__ beta,
                                            float* __restrict__ out) {
    __shared__ float tile[64][65];
    __shared__ float sa[64], sb[64];
    int lane = threadIdx.x & 63, wid = threadIdx.x >> 6;
    int b = blockIdx.x >> 7, nt = blockIdx.x & 127;
    int n0 = nt * 64;
    if (threadIdx.x < 64) {
        const float inv = 1.f / 32768.f;
        float mean = sums[threadIdx.x] * inv;
        float var = sums[64 + threadIdx.x] * inv - mean * mean;
        float rs = rsqrtf(var + 1e-5f);
        float a = rs * gamma[threadIdx.x];
        sa[threadIdx.x] = a;
        sb[threadIdx.x] = beta[threadIdx.x] - mean * a;
    }
    for (int rr = 0; rr < 16; ++rr) {
        int r = wid * 16 + rr;
        tile[r][lane] = outp[((size_t)(b * NPTS + n0 + r)) * 64 + lane];
    }
    __syncthreads();
    for (int rr = 0; rr < 16; ++rr) {
        int dr = wid * 16 + rr;
        out[((size_t)b * 64 + dr) * NPTS + n0 + lane] =
            fmaf(tile[lane][dr], sa[dr], sb[dr]);
    }
}

extern "C" void kernel_launch(void* const* d_in, const int* in_sizes, int n_in,
                              void* d_out, int out_size, void* d_ws, size_t ws_size,
                              hipStream_t stream) {
    (void)in_sizes; (void)n_in; (void)out_size; (void)ws_size;
    const float* x     = (const float*)d_in[0];  // (4,64,8192)
    const float* pos   = (const float*)d_in[1];  // (4,3,8192)
    const float* F     = (const float*)d_in[2];  // (16,64,64)
    const float* gamma = (const float*)d_in[3];  // (64,)
    const float* beta  = (const float*)d_in[4];  // (64,)
    float* out = (float*)d_out;                  // (4,64,8192)

    char* ws = (char*)d_ws;
    float* xT   = (float*)(ws + OFF_XT);
    float* Fb   = (float*)(ws + OFF_FBIG);
    float* sums = (float*)(ws + OFF_SUMS);
    int*   idx  = (int*)(ws + OFF_IDX);
    float* pre  = (float*)(ws + OFF_PRE);
    float* sqa  = (float*)(ws + OFF_SQ);   // aliases pre; consumed before conv

    k_prep<<<658, 256, 0, stream>>>(x, F, pos, xT, Fb, sums, sqa);
    k_knn<<<2048, 256, 0, stream>>>(pos, sqa, idx);
    k_conv<<<512, 256, 0, stream>>>(xT, Fb, idx, pre, sums);
    k_bn<<<512, 256, 0, stream>>>(pre, sums, gamma, beta, out);
}